// Round 2
// baseline (947.462 us; speedup 1.0000x reference)
//
#include <hip/hip_runtime.h>
#include <hip/hip_bf16.h>

// ---------- types / helpers ----------
typedef unsigned short u16;
typedef __bf16  bf16x8 __attribute__((ext_vector_type(8)));
typedef float   f32x4  __attribute__((ext_vector_type(4)));
typedef unsigned int   u32x4 __attribute__((ext_vector_type(4)));
typedef unsigned short u16x4 __attribute__((ext_vector_type(4)));

union FragU { bf16x8 v; u16 u[8]; u32x4 q; };

__device__ __forceinline__ float b2f(u16 u) {
    unsigned int x = ((unsigned int)u) << 16;
    return __builtin_bit_cast(float, x);
}
__device__ __forceinline__ u16 f2b(float f) {
    unsigned int x = __builtin_bit_cast(unsigned int, f);
    unsigned int r = (x + 0x7fffu + ((x >> 16) & 1u)) >> 16;
    return (u16)r;
}
__device__ __forceinline__ float rcp_(float x) { return __builtin_amdgcn_rcpf(x); }
__device__ __forceinline__ float sigm_(float x) { return rcp_(1.0f + __expf(-x)); }
__device__ __forceinline__ float tanh_(float x) {
    float e = __expf(2.0f * x);
    return 1.0f - 2.0f * rcp_(e + 1.0f);
}
__device__ __forceinline__ bf16x8 load_afrag(const u16* s) {
    FragU f; f.q = *(const u32x4*)s; return f.v;
}
__device__ __forceinline__ f32x4 mfma16(bf16x8 a, bf16x8 b, f32x4 c) {
    return __builtin_amdgcn_mfma_f32_16x16x32_bf16(a, b, c, 0, 0, 0);
}
// split helper: hi bf16 + residual lo bf16
__device__ __forceinline__ void split2(float f, u16& hi, u16& lo) {
    hi = f2b(f); lo = f2b(f - b2f(hi));
}

// ---------------------------------------------------------------------------
// Split-bf16 GEMM (effective-fp32): out = A @ W + bias  (3 MFMAs per product)
// MODE 0: vocab-enc  A[256,128] = src_emb,      out xpv fp32 [256,192]
// MODE 1: vocab-dec  A[256,64]  = out_W^T * 8,  out xpv fp32 [256,192]
// MODE 2: enc_proj   A = fwd+bwd (4 bf16 planes), K=64,N=64,
//         out bf16 TRANSPOSED encpT[(b*64+col)*32+s] = (acc+be)*2
// MODE 3: logits     A = hid hi/lo planes, K=64,N=256, out fp32 d_out
// Block 256 thr, 64 rows; wave w covers cols [w*N/4,(w+1)*N/4)
// ---------------------------------------------------------------------------
template<int MODE, int K, int N>
__global__ __launch_bounds__(256, (MODE >= 2) ? 2 : 1) void gemm_hl(
    const float* __restrict__ srcf, const u16* __restrict__ sh,
    const u16* __restrict__ sl, const u16* __restrict__ sh2,
    const u16* __restrict__ sl2, const float* __restrict__ W,
    const float* __restrict__ bias, float* __restrict__ outf,
    u16* __restrict__ outh)
{
    constexpr int KP = K + 8;
    constexpr int LK = (K == 128) ? 7 : 6;
    __shared__ __attribute__((aligned(16))) u16 Ash[64 * KP];
    __shared__ __attribute__((aligned(16))) u16 Asl[64 * KP];

    const int tid  = threadIdx.x;
    const int lane = tid & 63, w = tid >> 6;
    const int q = lane >> 4, ln = lane & 15;
    const int rbase = blockIdx.x * 64;

    // ---- stage A rows into LDS hi/lo ----
    for (int i = tid; i < 64 * K; i += 256) {
        int r = i >> LK, c = i & (K - 1);
        int rg = rbase + r;
        float f;
        if constexpr (MODE == 0)      f = srcf[rg * K + c];
        else if constexpr (MODE == 1) f = srcf[c * 256 + rg] * 8.0f;
        else if constexpr (MODE == 2)
            f = b2f(sh[rg * 64 + c]) + b2f(sl[rg * 64 + c])
              + b2f(sh2[rg * 64 + c]) + b2f(sl2[rg * 64 + c]);
        else                          f = b2f(sh[rg * 64 + c]) + b2f(sl[rg * 64 + c]);
        u16 hi, lo; split2(f, hi, lo);
        Ash[r * KP + c] = hi; Asl[r * KP + c] = lo;
    }

    // ---- B fragments hi/lo in registers ----
    constexpr int NT  = N / 64;
    constexpr int NKF = K / 32;
    FragU bfh[NT][NKF], bfl[NT][NKF];
    float bv[NT];
    const int cw = w * (N >> 2);
#pragma unroll
    for (int tl = 0; tl < NT; ++tl) {
        int col = cw + tl * 16 + ln;
#pragma unroll
        for (int kf = 0; kf < NKF; ++kf)
#pragma unroll
            for (int j = 0; j < 8; ++j) {
                float f = W[(kf * 32 + q * 8 + j) * N + col];
                split2(f, bfh[tl][kf].u[j], bfl[tl][kf].u[j]);
            }
        bv[tl] = bias[col];
    }
    __syncthreads();

#pragma unroll
    for (int r = 0; r < 4; ++r) {
        bf16x8 afh[NKF], afl[NKF];
#pragma unroll
        for (int kf = 0; kf < NKF; ++kf) {
            afh[kf] = load_afrag(&Ash[(r * 16 + ln) * KP + kf * 32 + q * 8]);
            afl[kf] = load_afrag(&Asl[(r * 16 + ln) * KP + kf * 32 + q * 8]);
        }
#pragma unroll
        for (int tl = 0; tl < NT; ++tl) {
            f32x4 acc = {0.f, 0.f, 0.f, 0.f};
#pragma unroll
            for (int kf = 0; kf < NKF; ++kf) {
                acc = mfma16(afl[kf], bfh[tl][kf].v, acc);
                acc = mfma16(afh[kf], bfl[tl][kf].v, acc);
                acc = mfma16(afh[kf], bfh[tl][kf].v, acc);
            }
            const int col = cw + tl * 16 + ln;
#pragma unroll
            for (int i = 0; i < 4; ++i) {
                int rowg = rbase + r * 16 + q * 4 + i;
                float val = acc[i] + bv[tl];
                if constexpr (MODE == 2) {
                    int b = rowg >> 5, s2 = rowg & 31;
                    outh[(b * 64 + col) * 32 + s2] = f2b(val * 2.0f);
                } else if constexpr (MODE == 3) {
                    outf[rowg * N + col] = val;
                } else {
                    outf[rowg * 192 + col] = val;
                }
            }
        }
    }
}

// ---------------------------------------------------------------------------
// Fused bidirectional encoder GRU (split-bf16), 8 rows/block, 1024 blocks
// (blocks [0,512) = forward, [512,1024) = backward). Backward writes its own
// planes (bh/bl); fwd+bwd sum is folded into the MODE-2 gemm / dec staging.
// MFMA batch rows 8..15 are zero padding; writes guarded to q<2.
// ---------------------------------------------------------------------------
__global__ __launch_bounds__(256, 2) void enc8(
    const int* __restrict__ src_ids, const float* __restrict__ xf,
    const float* __restrict__ xb,
    const float* __restrict__ Uf_, const float* __restrict__ bf_,
    const float* __restrict__ Ub_, const float* __restrict__ bb_,
    u16* __restrict__ fh, u16* __restrict__ fl,
    u16* __restrict__ bh, u16* __restrict__ bl)
{
    __shared__ __attribute__((aligned(16))) u16 hsh[16 * 72];
    __shared__ __attribute__((aligned(16))) u16 hsl[16 * 72];
    const int tid  = threadIdx.x;
    const int lane = tid & 63, w = tid >> 6;
    const int q = lane >> 4, ln = lane & 15;
    const int dir = (int)(blockIdx.x >> 9);
    const int b0  = (int)(blockIdx.x & 511) * 8;
    const float* xpv = dir ? xb  : xf;
    const float* U   = dir ? Ub_ : Uf_;
    const float* b_  = dir ? bb_ : bf_;
    u16* oh = dir ? bh : fh;
    u16* ol = dir ? bl : fl;
    const int jw = w * 16;
    const bool rowok = (q < 2);

    for (int i = tid; i < 16 * 64; i += 256) {
        int r = i >> 6, c = i & 63;
        hsh[r * 72 + c] = 0; hsl[r * 72 + c] = 0;
    }
    FragU ufh[3][2], ufl[3][2];
    float b1[3];
#pragma unroll
    for (int g = 0; g < 3; ++g) {
        int col = g * 64 + jw + ln;
#pragma unroll
        for (int kf = 0; kf < 2; ++kf)
#pragma unroll
            for (int j = 0; j < 8; ++j) {
                float f = U[(kf * 32 + q * 8 + j) * 192 + col];
                split2(f, ufh[g][kf].u[j], ufl[g][kf].u[j]);
            }
        b1[g] = b_[192 + col];
    }
    float hp[4] = {0, 0, 0, 0};

    // prefetch x-gates for first step (rows clamped in-bounds for pad lanes)
    float xg[3][4];
    {
        const int s0 = dir ? 31 : 0;
#pragma unroll
        for (int i = 0; i < 4; ++i) {
            int rowv = b0 + ((q * 4 + i) & 7);
            int id = src_ids[rowv * 32 + s0];
#pragma unroll
            for (int g = 0; g < 3; ++g) xg[g][i] = xpv[id * 192 + g * 64 + jw + ln];
        }
    }
    __syncthreads();

    for (int step = 0; step < 32; ++step) {
        const int s = dir ? (31 - step) : step;
        // prefetch next step's x-gates
        float xgn[3][4];
        {
            int sn = dir ? (step >= 31 ? 0 : 30 - step) : (step >= 31 ? 31 : step + 1);
#pragma unroll
            for (int i = 0; i < 4; ++i) {
                int rowv = b0 + ((q * 4 + i) & 7);
                int id = src_ids[rowv * 32 + sn];
#pragma unroll
                for (int g = 0; g < 3; ++g) xgn[g][i] = xpv[id * 192 + g * 64 + jw + ln];
            }
        }
        bf16x8 a0h = load_afrag(&hsh[ln * 72 + q * 8]);
        bf16x8 a1h = load_afrag(&hsh[ln * 72 + 32 + q * 8]);
        bf16x8 a0l = load_afrag(&hsl[ln * 72 + q * 8]);
        bf16x8 a1l = load_afrag(&hsl[ln * 72 + 32 + q * 8]);
        f32x4 acc[3];
#pragma unroll
        for (int g = 0; g < 3; ++g) {
            f32x4 a = {0.f, 0.f, 0.f, 0.f};
            a = mfma16(a0l, ufh[g][0].v, a);
            a = mfma16(a0h, ufl[g][0].v, a);
            a = mfma16(a0h, ufh[g][0].v, a);
            a = mfma16(a1l, ufh[g][1].v, a);
            a = mfma16(a1h, ufl[g][1].v, a);
            a = mfma16(a1h, ufh[g][1].v, a);
            acc[g] = a;
        }
        float nh[4];
#pragma unroll
        for (int i = 0; i < 4; ++i) {
            const int rowg = b0 + q * 4 + i;
            float zz = sigm_(xg[0][i] + acc[0][i] + b1[0]);
            float rr = sigm_(xg[1][i] + acc[1][i] + b1[1]);
            float nn = tanh_(xg[2][i] + rr * (acc[2][i] + b1[2]));
            nh[i] = zz * hp[i] + (1.0f - zz) * nn;  hp[i] = nh[i];
            if (rowok) {
                const int gidx = (rowg * 32 + s) * 64 + jw + ln;
                u16 hi, lo; split2(nh[i], hi, lo);
                oh[gidx] = hi; ol[gidx] = lo;
            }
        }
        __syncthreads();
        if (rowok) {
#pragma unroll
            for (int i = 0; i < 4; ++i) {
                u16 hi, lo; split2(nh[i], hi, lo);
                hsh[(q * 4 + i) * 72 + jw + ln] = hi;
                hsl[(q * 4 + i) * 72 + jw + ln] = lo;
            }
        }
        __syncthreads();
#pragma unroll
        for (int g = 0; g < 3; ++g)
#pragma unroll
            for (int i = 0; i < 4; ++i) xg[g][i] = xgn[g][i];
    }
}

// ---------------------------------------------------------------------------
// Decoder: Bahdanau attention + GRU, split-bf16; 8 rows/block, 512 blocks
// (2 blocks/CU -> 2 waves/SIMD). encoded (fp32, 4-plane sum) staged in LDS
// once (64 KiB). exp split: exp(2(d+e)) = exp(2d)[LDS, 4/thr/step] *
// exp(2e)[VGPR cache, step-invariant] -> scores loop has 1 trans/element.
// ---------------------------------------------------------------------------
__global__ __launch_bounds__(256, 2) void dec_kernel(
    const int* __restrict__ tgt_ids, const float* __restrict__ xpvd,
    const u16* __restrict__ fh, const u16* __restrict__ fl,
    const u16* __restrict__ bh, const u16* __restrict__ bl,
    const u16* __restrict__ encpT,
    const float* __restrict__ dec_U, const float* __restrict__ dec_W,
    const float* __restrict__ dec_b,
    const float* __restrict__ Wd, const float* __restrict__ bd,
    const float* __restrict__ v_, const float* __restrict__ bv_,
    u16* __restrict__ hid_hi, u16* __restrict__ hid_lo)
{
    __shared__ __attribute__((aligned(16))) float enc_lds[8 * 2048]; // 64 KiB
    __shared__ __attribute__((aligned(16))) u16 hqh[16 * 72];
    __shared__ __attribute__((aligned(16))) u16 hql[16 * 72];
    __shared__ __attribute__((aligned(16))) u16 cxh[16 * 72];
    __shared__ __attribute__((aligned(16))) u16 cxl[16 * 72];
    __shared__ __attribute__((aligned(16))) float edl[8 * 72];       // exp(2*dproj)
    __shared__ float wl[8 * 36];
    __shared__ float vl[64];
    const int tid  = threadIdx.x;
    const int lane = tid & 63, w = tid >> 6;
    const int q = lane >> 4, ln = lane & 15;
    const int b0 = blockIdx.x * 8;
    const int jw = w * 16;
    const bool rowok = (q < 2);

    // ---- stage encoded = fwd_hi+fwd_lo+bwd_hi+bwd_lo (fp32) into LDS ----
    {
        const u16* g0 = fh + (size_t)b0 * 2048;
        const u16* g1 = fl + (size_t)b0 * 2048;
        const u16* g2 = bh + (size_t)b0 * 2048;
        const u16* g3 = bl + (size_t)b0 * 2048;
        for (int i = tid; i < 8 * 2048 / 4; i += 256) {
            u16x4 v0 = *(const u16x4*)(g0 + i * 4);
            u16x4 v1 = *(const u16x4*)(g1 + i * 4);
            u16x4 v2 = *(const u16x4*)(g2 + i * 4);
            u16x4 v3 = *(const u16x4*)(g3 + i * 4);
            f32x4 f;
#pragma unroll
            for (int k = 0; k < 4; ++k)
                f[k] = (b2f(v0[k]) + b2f(v1[k])) + (b2f(v2[k]) + b2f(v3[k]));
            *(f32x4*)(&enc_lds[i * 4]) = f;
        }
    }
    if (tid < 64) vl[tid] = v_[tid];
    const float bv0 = bv_[0];

    FragU wdh[2], wdl[2], ufh[3][2], ufl[3][2], wch[3][2], wcl[3][2];
    float b1[3];
#pragma unroll
    for (int kf = 0; kf < 2; ++kf)
#pragma unroll
        for (int j = 0; j < 8; ++j) {
            float f = Wd[(kf * 32 + q * 8 + j) * 64 + jw + ln];
            split2(f, wdh[kf].u[j], wdl[kf].u[j]);
        }
#pragma unroll
    for (int g = 0; g < 3; ++g) {
        int col = g * 64 + jw + ln;
#pragma unroll
        for (int kf = 0; kf < 2; ++kf)
#pragma unroll
            for (int j = 0; j < 8; ++j) {
                int k = kf * 32 + q * 8 + j;
                float fu = dec_U[k * 192 + col];
                split2(fu, ufh[g][kf].u[j], ufl[g][kf].u[j]);
                float fc = dec_W[(64 + k) * 192 + col];
                split2(fc, wch[g][kf].u[j], wcl[g][kf].u[j]);
            }
        b1[g] = dec_b[192 + col];
    }
    const float bd_ = bd[jw + ln];

    // ---- step-invariant exp(2e) cache in VGPRs: this thread's (b,s) pair ----
    float Ee[64];
    {
        const int bb2 = tid >> 5, ss = tid & 31;
        const u16* ep = &encpT[(size_t)(b0 + bb2) * 2048 + ss];
#pragma unroll
        for (int a = 0; a < 64; ++a) Ee[a] = __expf(b2f(ep[a * 32]));
    }

    // prefetch t=0 x-gates (BOW = 1 for all rows)
    float xg[3][4];
#pragma unroll
    for (int g = 0; g < 3; ++g) {
        float f = xpvd[1 * 192 + g * 64 + jw + ln];
#pragma unroll
        for (int i = 0; i < 4; ++i) xg[g][i] = f;
    }
    __syncthreads();   // enc_lds ready

    // SVB = bias_v + sum_a v[a]   (logit = SVB - 2 * sum_a v[a]/(E+1))
    float SVB = bv0;
#pragma unroll
    for (int a = 0; a < 64; ++a) SVB += vl[a];

    // h0 = encoded[:,0]; zero-pad rows 8..15 of h and ctx tiles
    for (int i = tid; i < 16 * 64; i += 256) {
        int r = i >> 6, c = i & 63;
        if (r < 8) {
            u16 hi, lo; split2(enc_lds[r * 2048 + c], hi, lo);
            hqh[r * 72 + c] = hi; hql[r * 72 + c] = lo;
        } else {
            hqh[r * 72 + c] = 0; hql[r * 72 + c] = 0;
            cxh[r * 72 + c] = 0; cxl[r * 72 + c] = 0;
        }
    }
    float hp[4];
#pragma unroll
    for (int i = 0; i < 4; ++i)
        hp[i] = rowok ? enc_lds[(q * 4 + i) * 2048 + jw + ln] : 0.f;
    __syncthreads();

    for (int t = 0; t < 32; ++t) {
        // prefetch next step's x-gates: dec_in[t+1] = tgt[t]
        float xgn[3][4];
        {
            int tn = (t >= 31) ? 30 : t;
#pragma unroll
            for (int i = 0; i < 4; ++i) {
                int rowv = b0 + ((q * 4 + i) & 7);
                int id = tgt_ids[rowv * 32 + tn];
#pragma unroll
                for (int g = 0; g < 3; ++g) xgn[g][i] = xpvd[id * 192 + g * 64 + jw + ln];
            }
        }
        bf16x8 ah0 = load_afrag(&hqh[ln * 72 + q * 8]);
        bf16x8 ah1 = load_afrag(&hqh[ln * 72 + 32 + q * 8]);
        bf16x8 al0 = load_afrag(&hql[ln * 72 + q * 8]);
        bf16x8 al1 = load_afrag(&hql[ln * 72 + 32 + q * 8]);
        // edl = exp(2*(h@Wd + bd))
        {
            f32x4 a = {0.f, 0.f, 0.f, 0.f};
            a = mfma16(al0, wdh[0].v, a);
            a = mfma16(ah0, wdl[0].v, a);
            a = mfma16(ah0, wdh[0].v, a);
            a = mfma16(al1, wdh[1].v, a);
            a = mfma16(ah1, wdl[1].v, a);
            a = mfma16(ah1, wdh[1].v, a);
            if (rowok) {
#pragma unroll
                for (int i = 0; i < 4; ++i)
                    edl[(q * 4 + i) * 72 + jw + ln] = __expf((a[i] + bd_) * 2.0f);
            }
        }
        __syncthreads();
        // scores + softmax over S: E = E_d * E_e; tanh = 1 - 2/(E+1)
        {
            const int bb2 = tid >> 5, sidx = tid & 31;
            const float* dp = &edl[bb2 * 72];
            float av0 = 0.f, av1 = 0.f, av2 = 0.f, av3 = 0.f;
#pragma unroll
            for (int a4 = 0; a4 < 16; ++a4) {
                f32x4 dv = *(const f32x4*)(dp + a4 * 4);
                av0 += vl[a4 * 4 + 0] * rcp_(__builtin_fmaf(dv[0], Ee[a4 * 4 + 0], 1.0f));
                av1 += vl[a4 * 4 + 1] * rcp_(__builtin_fmaf(dv[1], Ee[a4 * 4 + 1], 1.0f));
                av2 += vl[a4 * 4 + 2] * rcp_(__builtin_fmaf(dv[2], Ee[a4 * 4 + 2], 1.0f));
                av3 += vl[a4 * 4 + 3] * rcp_(__builtin_fmaf(dv[3], Ee[a4 * 4 + 3], 1.0f));
            }
            float logit = SVB - 2.0f * ((av0 + av1) + (av2 + av3));
            float m = logit;
#pragma unroll
            for (int off = 16; off > 0; off >>= 1) m = fmaxf(m, __shfl_xor(m, off, 32));
            float e2 = __expf(logit - m);
            float ssum = e2;
#pragma unroll
            for (int off = 16; off > 0; off >>= 1) ssum += __shfl_xor(ssum, off, 32);
            wl[bb2 * 36 + sidx] = e2 * rcp_(ssum);
        }
        __syncthreads();
        // ctx = sum_s w[s] * encoded[b,s,:]  — LDS-only, wave-per-row sweep
#pragma unroll
        for (int rr2 = 0; rr2 < 2; ++rr2) {
            const int b = rr2 * 4 + w;
            float c0 = 0.f, c1 = 0.f, c2 = 0.f, c3 = 0.f;
#pragma unroll
            for (int s4 = 0; s4 < 8; ++s4) {
                const int s = s4 * 4 + q;
                const float ww = wl[b * 36 + s];
                f32x4 ev = *(const f32x4*)(&enc_lds[b * 2048 + s * 64 + ln * 4]);
                c0 += ww * ev[0]; c1 += ww * ev[1];
                c2 += ww * ev[2]; c3 += ww * ev[3];
            }
            c0 += __shfl_xor(c0, 16); c0 += __shfl_xor(c0, 32);
            c1 += __shfl_xor(c1, 16); c1 += __shfl_xor(c1, 32);
            c2 += __shfl_xor(c2, 16); c2 += __shfl_xor(c2, 32);
            c3 += __shfl_xor(c3, 16); c3 += __shfl_xor(c3, 32);
            if (q == 0) {
                u16x4 vh, vo;
                u16 th, tl2;
                split2(c0, th, tl2); vh[0] = th; vo[0] = tl2;
                split2(c1, th, tl2); vh[1] = th; vo[1] = tl2;
                split2(c2, th, tl2); vh[2] = th; vo[2] = tl2;
                split2(c3, th, tl2); vh[3] = th; vo[3] = tl2;
                *(u16x4*)(&cxh[b * 72 + ln * 4]) = vh;
                *(u16x4*)(&cxl[b * 72 + ln * 4]) = vo;
            }
        }
        __syncthreads();
        // GRU gates: ax[g] = ctx@Wc (input path), ahh[g] = h@U (recurrent)
        bf16x8 ac0 = load_afrag(&cxh[ln * 72 + q * 8]);
        bf16x8 ac1 = load_afrag(&cxh[ln * 72 + 32 + q * 8]);
        bf16x8 al2 = load_afrag(&cxl[ln * 72 + q * 8]);
        bf16x8 al3 = load_afrag(&cxl[ln * 72 + 32 + q * 8]);
        f32x4 ax[3], ahh[3];
#pragma unroll
        for (int g = 0; g < 3; ++g) {
            f32x4 a = {0.f, 0.f, 0.f, 0.f};
            a = mfma16(al2, wch[g][0].v, a);
            a = mfma16(ac0, wcl[g][0].v, a);
            a = mfma16(ac0, wch[g][0].v, a);
            a = mfma16(al3, wch[g][1].v, a);
            a = mfma16(ac1, wcl[g][1].v, a);
            a = mfma16(ac1, wch[g][1].v, a);
            ax[g] = a;
            f32x4 h = {0.f, 0.f, 0.f, 0.f};
            h = mfma16(al0, ufh[g][0].v, h);
            h = mfma16(ah0, ufl[g][0].v, h);
            h = mfma16(ah0, ufh[g][0].v, h);
            h = mfma16(al1, ufh[g][1].v, h);
            h = mfma16(ah1, ufl[g][1].v, h);
            h = mfma16(ah1, ufh[g][1].v, h);
            ahh[g] = h;
        }
        float nh[4];
#pragma unroll
        for (int i = 0; i < 4; ++i) {
            int rowg = b0 + q * 4 + i;
            float zz = sigm_(xg[0][i] + ax[0][i] + ahh[0][i] + b1[0]);
            float rr = sigm_(xg[1][i] + ax[1][i] + ahh[1][i] + b1[1]);
            float nn = tanh_(xg[2][i] + ax[2][i] + rr * (ahh[2][i] + b1[2]));
            nh[i] = zz * hp[i] + (1.0f - zz) * nn;  hp[i] = nh[i];
            if (rowok) {
                int gidx = (rowg * 32 + t) * 64 + jw + ln;
                u16 hi, lo; split2(nh[i], hi, lo);
                hid_hi[gidx] = hi; hid_lo[gidx] = lo;
                hqh[(q * 4 + i) * 72 + jw + ln] = hi;
                hql[(q * 4 + i) * 72 + jw + ln] = lo;
            }
        }
        // note: h-tile writes are safe here — all hq reads happened before
        // barrier 1 of this step; barrier below orders them for step t+1.
        __syncthreads();
#pragma unroll
        for (int g = 0; g < 3; ++g)
#pragma unroll
            for (int i = 0; i < 4; ++i) xg[g][i] = xgn[g][i];
    }
}

// ---------------------------------------------------------------------------
extern "C" void kernel_launch(void* const* d_in, const int* in_sizes, int n_in,
                              void* d_out, int out_size, void* d_ws, size_t ws_size,
                              hipStream_t stream) {
    const int*   src_ids = (const int*)d_in[0];
    const int*   tgt_ids = (const int*)d_in[1];
    const float* src_emb = (const float*)d_in[2];
    const float* enc_Wf  = (const float*)d_in[3];
    const float* enc_Uf  = (const float*)d_in[4];
    const float* enc_bf  = (const float*)d_in[5];
    const float* enc_Wb  = (const float*)d_in[6];
    const float* enc_Ub  = (const float*)d_in[7];
    const float* enc_bb  = (const float*)d_in[8];
    const float* attn_We = (const float*)d_in[9];
    const float* attn_be = (const float*)d_in[10];
    const float* attn_Wd = (const float*)d_in[11];
    const float* attn_bd = (const float*)d_in[12];
    const float* attn_v  = (const float*)d_in[13];
    const float* attn_bv = (const float*)d_in[14];
    const float* dec_W   = (const float*)d_in[15];
    const float* dec_U   = (const float*)d_in[16];
    const float* dec_b   = (const float*)d_in[17];
    const float* out_W   = (const float*)d_in[18];
    const float* out_b   = (const float*)d_in[19];

    // ws layout (u16 units). fwd [0,16)/[16,32) MiB, bwd [32,48)/[48,64),
    // encpT [64,80), xpv_f/xpv_b/xpvd after 80 MiB. hid reuses fwd planes
    // (dec reads its own rows before overwriting them).
    u16* ws = (u16*)d_ws;
    u16* fwd_hi = ws;
    u16* fwd_lo = ws +  8388608;
    u16* bwd_hi = ws + 16777216;
    u16* bwd_lo = ws + 25165824;
    u16* encpT  = ws + 33554432;
    float* xpv_f = (float*)(ws + 41943040);
    float* xpv_b = (float*)(ws + 42041344);
    float* xpvd  = (float*)(ws + 42139648);
    u16* hid_hi = fwd_hi;
    u16* hid_lo = fwd_lo;

    dim3 blk(256);
    gemm_hl<0, 128, 192><<<4, blk, 0, stream>>>(
        src_emb, nullptr, nullptr, nullptr, nullptr, enc_Wf, enc_bf, xpv_f, nullptr);
    gemm_hl<0, 128, 192><<<4, blk, 0, stream>>>(
        src_emb, nullptr, nullptr, nullptr, nullptr, enc_Wb, enc_bb, xpv_b, nullptr);
    gemm_hl<1, 64, 192><<<4, blk, 0, stream>>>(
        out_W, nullptr, nullptr, nullptr, nullptr, dec_W, dec_b, xpvd, nullptr);
    enc8<<<1024, blk, 0, stream>>>(src_ids, xpv_f, xpv_b, enc_Uf, enc_bf,
                                   enc_Ub, enc_bb, fwd_hi, fwd_lo, bwd_hi, bwd_lo);
    gemm_hl<2, 64, 64><<<2048, blk, 0, stream>>>(
        nullptr, fwd_hi, fwd_lo, bwd_hi, bwd_lo, attn_We, attn_be, nullptr, encpT);
    dec_kernel<<<512, blk, 0, stream>>>(tgt_ids, xpvd, fwd_hi, fwd_lo, bwd_hi,
                                        bwd_lo, encpT, dec_U, dec_W, dec_b,
                                        attn_Wd, attn_bd, attn_v, attn_bv,
                                        hid_hi, hid_lo);
    gemm_hl<3, 64, 256><<<2048, blk, 0, stream>>>(
        nullptr, hid_hi, hid_lo, nullptr, nullptr, out_W, out_b, (float*)d_out, nullptr);
}

// Round 3
// 591.936 us; speedup vs baseline: 1.6006x; 1.6006x over previous
//
#include <hip/hip_runtime.h>
#include <hip/hip_bf16.h>

// ---------- types / helpers ----------
typedef unsigned short u16;
typedef __bf16  bf16x8 __attribute__((ext_vector_type(8)));
typedef float   f32x4  __attribute__((ext_vector_type(4)));
typedef unsigned int   u32x4 __attribute__((ext_vector_type(4)));
typedef unsigned short u16x4 __attribute__((ext_vector_type(4)));

union FragU { bf16x8 v; u16 u[8]; u32x4 q; };

__device__ __forceinline__ float b2f(u16 u) {
    unsigned int x = ((unsigned int)u) << 16;
    return __builtin_bit_cast(float, x);
}
__device__ __forceinline__ u16 f2b(float f) {
    unsigned int x = __builtin_bit_cast(unsigned int, f);
    unsigned int r = (x + 0x7fffu + ((x >> 16) & 1u)) >> 16;
    return (u16)r;
}
__device__ __forceinline__ float rcp_(float x) { return __builtin_amdgcn_rcpf(x); }
__device__ __forceinline__ float sigm_(float x) { return rcp_(1.0f + __expf(-x)); }
__device__ __forceinline__ float tanh_(float x) {
    float e = __expf(2.0f * x);
    return 1.0f - 2.0f * rcp_(e + 1.0f);
}
__device__ __forceinline__ bf16x8 load_afrag(const u16* s) {
    FragU f; f.q = *(const u32x4*)s; return f.v;
}
__device__ __forceinline__ f32x4 mfma16(bf16x8 a, bf16x8 b, f32x4 c) {
    return __builtin_amdgcn_mfma_f32_16x16x32_bf16(a, b, c, 0, 0, 0);
}
// split helper: hi bf16 + residual lo bf16
__device__ __forceinline__ void split2(float f, u16& hi, u16& lo) {
    hi = f2b(f); lo = f2b(f - b2f(hi));
}

// ---------------------------------------------------------------------------
// Split-bf16 GEMM (effective-fp32): out = A @ W + bias  (3 MFMAs per product)
// MODE 0: vocab-enc  A[256,128] = src_emb,      out xpv fp32 [256,192]
// MODE 1: vocab-dec  A[256,64]  = out_W^T * 8,  out xpv fp32 [256,192]
// MODE 2: enc_proj   A = fwd+bwd (4 bf16 planes), K=64,N=64,
//         out bf16 TRANSPOSED encpT[(b*64+col)*32+s] = (acc+be)*2
// MODE 3: logits     A = hid hi/lo planes, K=64,N=256, out fp32 d_out
// Block 256 thr, 64 rows; wave w covers cols [w*N/4,(w+1)*N/4)
// ---------------------------------------------------------------------------
template<int MODE, int K, int N>
__global__ __launch_bounds__(256, (MODE >= 2) ? 2 : 1) void gemm_hl(
    const float* __restrict__ srcf, const u16* __restrict__ sh,
    const u16* __restrict__ sl, const u16* __restrict__ sh2,
    const u16* __restrict__ sl2, const float* __restrict__ W,
    const float* __restrict__ bias, float* __restrict__ outf,
    u16* __restrict__ outh)
{
    constexpr int KP = K + 8;
    constexpr int LK = (K == 128) ? 7 : 6;
    __shared__ __attribute__((aligned(16))) u16 Ash[64 * KP];
    __shared__ __attribute__((aligned(16))) u16 Asl[64 * KP];

    const int tid  = threadIdx.x;
    const int lane = tid & 63, w = tid >> 6;
    const int q = lane >> 4, ln = lane & 15;
    const int rbase = blockIdx.x * 64;

    // ---- stage A rows into LDS hi/lo ----
    for (int i = tid; i < 64 * K; i += 256) {
        int r = i >> LK, c = i & (K - 1);
        int rg = rbase + r;
        float f;
        if constexpr (MODE == 0)      f = srcf[rg * K + c];
        else if constexpr (MODE == 1) f = srcf[c * 256 + rg] * 8.0f;
        else if constexpr (MODE == 2)
            f = b2f(sh[rg * 64 + c]) + b2f(sl[rg * 64 + c])
              + b2f(sh2[rg * 64 + c]) + b2f(sl2[rg * 64 + c]);
        else                          f = b2f(sh[rg * 64 + c]) + b2f(sl[rg * 64 + c]);
        u16 hi, lo; split2(f, hi, lo);
        Ash[r * KP + c] = hi; Asl[r * KP + c] = lo;
    }

    // ---- B fragments hi/lo in registers ----
    constexpr int NT  = N / 64;
    constexpr int NKF = K / 32;
    FragU bfh[NT][NKF], bfl[NT][NKF];
    float bv[NT];
    const int cw = w * (N >> 2);
#pragma unroll
    for (int tl = 0; tl < NT; ++tl) {
        int col = cw + tl * 16 + ln;
#pragma unroll
        for (int kf = 0; kf < NKF; ++kf)
#pragma unroll
            for (int j = 0; j < 8; ++j) {
                float f = W[(kf * 32 + q * 8 + j) * N + col];
                split2(f, bfh[tl][kf].u[j], bfl[tl][kf].u[j]);
            }
        bv[tl] = bias[col];
    }
    __syncthreads();

#pragma unroll
    for (int r = 0; r < 4; ++r) {
        bf16x8 afh[NKF], afl[NKF];
#pragma unroll
        for (int kf = 0; kf < NKF; ++kf) {
            afh[kf] = load_afrag(&Ash[(r * 16 + ln) * KP + kf * 32 + q * 8]);
            afl[kf] = load_afrag(&Asl[(r * 16 + ln) * KP + kf * 32 + q * 8]);
        }
#pragma unroll
        for (int tl = 0; tl < NT; ++tl) {
            f32x4 acc = {0.f, 0.f, 0.f, 0.f};
#pragma unroll
            for (int kf = 0; kf < NKF; ++kf) {
                acc = mfma16(afl[kf], bfh[tl][kf].v, acc);
                acc = mfma16(afh[kf], bfl[tl][kf].v, acc);
                acc = mfma16(afh[kf], bfh[tl][kf].v, acc);
            }
            const int col = cw + tl * 16 + ln;
#pragma unroll
            for (int i = 0; i < 4; ++i) {
                int rowg = rbase + r * 16 + q * 4 + i;
                float val = acc[i] + bv[tl];
                if constexpr (MODE == 2) {
                    int b = rowg >> 5, s2 = rowg & 31;
                    outh[(b * 64 + col) * 32 + s2] = f2b(val * 2.0f);
                } else if constexpr (MODE == 3) {
                    outf[rowg * N + col] = val;
                } else {
                    outf[rowg * 192 + col] = val;
                }
            }
        }
    }
}

// ---------------------------------------------------------------------------
// Fused bidirectional encoder GRU (split-bf16), 8 rows/block, 1024 blocks
// (blocks [0,512) = forward, [512,1024) = backward). Backward writes its own
// planes (bh/bl); fwd+bwd sum is folded into the MODE-2 gemm / dec staging.
// MFMA batch rows 8..15 are zero padding; writes guarded to q<2.
// Register demand ~125 fits the 128-cap from (256,2) without spilling.
// ---------------------------------------------------------------------------
__global__ __launch_bounds__(256, 2) void enc8(
    const int* __restrict__ src_ids, const float* __restrict__ xf,
    const float* __restrict__ xb,
    const float* __restrict__ Uf_, const float* __restrict__ bf_,
    const float* __restrict__ Ub_, const float* __restrict__ bb_,
    u16* __restrict__ fh, u16* __restrict__ fl,
    u16* __restrict__ bh, u16* __restrict__ bl)
{
    __shared__ __attribute__((aligned(16))) u16 hsh[16 * 72];
    __shared__ __attribute__((aligned(16))) u16 hsl[16 * 72];
    const int tid  = threadIdx.x;
    const int lane = tid & 63, w = tid >> 6;
    const int q = lane >> 4, ln = lane & 15;
    const int dir = (int)(blockIdx.x >> 9);
    const int b0  = (int)(blockIdx.x & 511) * 8;
    const float* xpv = dir ? xb  : xf;
    const float* U   = dir ? Ub_ : Uf_;
    const float* b_  = dir ? bb_ : bf_;
    u16* oh = dir ? bh : fh;
    u16* ol = dir ? bl : fl;
    const int jw = w * 16;
    const bool rowok = (q < 2);

    for (int i = tid; i < 16 * 64; i += 256) {
        int r = i >> 6, c = i & 63;
        hsh[r * 72 + c] = 0; hsl[r * 72 + c] = 0;
    }
    FragU ufh[3][2], ufl[3][2];
    float b1[3];
#pragma unroll
    for (int g = 0; g < 3; ++g) {
        int col = g * 64 + jw + ln;
#pragma unroll
        for (int kf = 0; kf < 2; ++kf)
#pragma unroll
            for (int j = 0; j < 8; ++j) {
                float f = U[(kf * 32 + q * 8 + j) * 192 + col];
                split2(f, ufh[g][kf].u[j], ufl[g][kf].u[j]);
            }
        b1[g] = b_[192 + col];
    }
    float hp[4] = {0, 0, 0, 0};

    // prefetch x-gates for first step (rows clamped in-bounds for pad lanes)
    float xg[3][4];
    {
        const int s0 = dir ? 31 : 0;
#pragma unroll
        for (int i = 0; i < 4; ++i) {
            int rowv = b0 + ((q * 4 + i) & 7);
            int id = src_ids[rowv * 32 + s0];
#pragma unroll
            for (int g = 0; g < 3; ++g) xg[g][i] = xpv[id * 192 + g * 64 + jw + ln];
        }
    }
    __syncthreads();

    for (int step = 0; step < 32; ++step) {
        const int s = dir ? (31 - step) : step;
        // prefetch next step's x-gates
        float xgn[3][4];
        {
            int sn = dir ? (step >= 31 ? 0 : 30 - step) : (step >= 31 ? 31 : step + 1);
#pragma unroll
            for (int i = 0; i < 4; ++i) {
                int rowv = b0 + ((q * 4 + i) & 7);
                int id = src_ids[rowv * 32 + sn];
#pragma unroll
                for (int g = 0; g < 3; ++g) xgn[g][i] = xpv[id * 192 + g * 64 + jw + ln];
            }
        }
        bf16x8 a0h = load_afrag(&hsh[ln * 72 + q * 8]);
        bf16x8 a1h = load_afrag(&hsh[ln * 72 + 32 + q * 8]);
        bf16x8 a0l = load_afrag(&hsl[ln * 72 + q * 8]);
        bf16x8 a1l = load_afrag(&hsl[ln * 72 + 32 + q * 8]);
        f32x4 acc[3];
#pragma unroll
        for (int g = 0; g < 3; ++g) {
            f32x4 a = {0.f, 0.f, 0.f, 0.f};
            a = mfma16(a0l, ufh[g][0].v, a);
            a = mfma16(a0h, ufl[g][0].v, a);
            a = mfma16(a0h, ufh[g][0].v, a);
            a = mfma16(a1l, ufh[g][1].v, a);
            a = mfma16(a1h, ufl[g][1].v, a);
            a = mfma16(a1h, ufh[g][1].v, a);
            acc[g] = a;
        }
        float nh[4];
#pragma unroll
        for (int i = 0; i < 4; ++i) {
            const int rowg = b0 + q * 4 + i;
            float zz = sigm_(xg[0][i] + acc[0][i] + b1[0]);
            float rr = sigm_(xg[1][i] + acc[1][i] + b1[1]);
            float nn = tanh_(xg[2][i] + rr * (acc[2][i] + b1[2]));
            nh[i] = zz * hp[i] + (1.0f - zz) * nn;  hp[i] = nh[i];
            if (rowok) {
                const int gidx = (rowg * 32 + s) * 64 + jw + ln;
                u16 hi, lo; split2(nh[i], hi, lo);
                oh[gidx] = hi; ol[gidx] = lo;
            }
        }
        __syncthreads();
        if (rowok) {
#pragma unroll
            for (int i = 0; i < 4; ++i) {
                u16 hi, lo; split2(nh[i], hi, lo);
                hsh[(q * 4 + i) * 72 + jw + ln] = hi;
                hsl[(q * 4 + i) * 72 + jw + ln] = lo;
            }
        }
        __syncthreads();
#pragma unroll
        for (int g = 0; g < 3; ++g)
#pragma unroll
            for (int i = 0; i < 4; ++i) xg[g][i] = xgn[g][i];
    }
}

// ---------------------------------------------------------------------------
// Decoder: Bahdanau attention + GRU, split-bf16; 8 rows/block, 512 blocks.
// launch_bounds(256,1): let the allocator use ~220 VGPRs (NO spill — the
// (256,2) cap at 128 VGPRs caused 567 MB of scratch traffic in R2). At
// ~220 VGPRs the HW still co-schedules 2 waves/SIMD (440 <= 512) and LDS
// (78.8 KiB) admits 2 blocks/CU -> occupancy without spill.
// exp split: exp(2(d+e)) = exp(2d)[LDS, 4/thr/step] * exp(2e)[VGPR cache,
// step-invariant] -> scores loop has 1 rcp + 1 fma per element.
// ---------------------------------------------------------------------------
__global__ __launch_bounds__(256, 1) void dec_kernel(
    const int* __restrict__ tgt_ids, const float* __restrict__ xpvd,
    const u16* __restrict__ fh, const u16* __restrict__ fl,
    const u16* __restrict__ bh, const u16* __restrict__ bl,
    const u16* __restrict__ encpT,
    const float* __restrict__ dec_U, const float* __restrict__ dec_W,
    const float* __restrict__ dec_b,
    const float* __restrict__ Wd, const float* __restrict__ bd,
    const float* __restrict__ v_, const float* __restrict__ bv_,
    u16* __restrict__ hid_hi, u16* __restrict__ hid_lo)
{
    __shared__ __attribute__((aligned(16))) float enc_lds[8 * 2048]; // 64 KiB
    __shared__ __attribute__((aligned(16))) u16 hqh[16 * 72];
    __shared__ __attribute__((aligned(16))) u16 hql[16 * 72];
    __shared__ __attribute__((aligned(16))) u16 cxh[16 * 72];
    __shared__ __attribute__((aligned(16))) u16 cxl[16 * 72];
    __shared__ __attribute__((aligned(16))) float edl[8 * 72];       // exp(2*dproj)
    __shared__ float wl[8 * 36];
    __shared__ float vl[64];
    const int tid  = threadIdx.x;
    const int lane = tid & 63, w = tid >> 6;
    const int q = lane >> 4, ln = lane & 15;
    const int b0 = blockIdx.x * 8;
    const int jw = w * 16;
    const bool rowok = (q < 2);

    // ---- stage encoded = fwd_hi+fwd_lo+bwd_hi+bwd_lo (fp32) into LDS ----
    {
        const u16* g0 = fh + (size_t)b0 * 2048;
        const u16* g1 = fl + (size_t)b0 * 2048;
        const u16* g2 = bh + (size_t)b0 * 2048;
        const u16* g3 = bl + (size_t)b0 * 2048;
        for (int i = tid; i < 8 * 2048 / 4; i += 256) {
            u16x4 v0 = *(const u16x4*)(g0 + i * 4);
            u16x4 v1 = *(const u16x4*)(g1 + i * 4);
            u16x4 v2 = *(const u16x4*)(g2 + i * 4);
            u16x4 v3 = *(const u16x4*)(g3 + i * 4);
            f32x4 f;
#pragma unroll
            for (int k = 0; k < 4; ++k)
                f[k] = (b2f(v0[k]) + b2f(v1[k])) + (b2f(v2[k]) + b2f(v3[k]));
            *(f32x4*)(&enc_lds[i * 4]) = f;
        }
    }
    if (tid < 64) vl[tid] = v_[tid];
    const float bv0 = bv_[0];

    FragU wdh[2], wdl[2], ufh[3][2], ufl[3][2], wch[3][2], wcl[3][2];
    float b1[3];
#pragma unroll
    for (int kf = 0; kf < 2; ++kf)
#pragma unroll
        for (int j = 0; j < 8; ++j) {
            float f = Wd[(kf * 32 + q * 8 + j) * 64 + jw + ln];
            split2(f, wdh[kf].u[j], wdl[kf].u[j]);
        }
#pragma unroll
    for (int g = 0; g < 3; ++g) {
        int col = g * 64 + jw + ln;
#pragma unroll
        for (int kf = 0; kf < 2; ++kf)
#pragma unroll
            for (int j = 0; j < 8; ++j) {
                int k = kf * 32 + q * 8 + j;
                float fu = dec_U[k * 192 + col];
                split2(fu, ufh[g][kf].u[j], ufl[g][kf].u[j]);
                float fc = dec_W[(64 + k) * 192 + col];
                split2(fc, wch[g][kf].u[j], wcl[g][kf].u[j]);
            }
        b1[g] = dec_b[192 + col];
    }
    const float bd_ = bd[jw + ln];

    // ---- step-invariant exp(2e) cache in VGPRs: this thread's (b,s) pair ----
    float Ee[64];
    {
        const int bb2 = tid >> 5, ss = tid & 31;
        const u16* ep = &encpT[(size_t)(b0 + bb2) * 2048 + ss];
#pragma unroll
        for (int a = 0; a < 64; ++a) Ee[a] = __expf(b2f(ep[a * 32]));
    }

    // prefetch t=0 x-gates (BOW = 1 for all rows)
    float xg[3][4];
#pragma unroll
    for (int g = 0; g < 3; ++g) {
        float f = xpvd[1 * 192 + g * 64 + jw + ln];
#pragma unroll
        for (int i = 0; i < 4; ++i) xg[g][i] = f;
    }
    __syncthreads();   // enc_lds ready

    // SVB = bias_v + sum_a v[a]   (logit = SVB - 2 * sum_a v[a]/(E+1))
    float SVB = bv0;
#pragma unroll
    for (int a = 0; a < 64; ++a) SVB += vl[a];

    // h0 = encoded[:,0]; zero-pad rows 8..15 of h and ctx tiles
    for (int i = tid; i < 16 * 64; i += 256) {
        int r = i >> 6, c = i & 63;
        if (r < 8) {
            u16 hi, lo; split2(enc_lds[r * 2048 + c], hi, lo);
            hqh[r * 72 + c] = hi; hql[r * 72 + c] = lo;
        } else {
            hqh[r * 72 + c] = 0; hql[r * 72 + c] = 0;
            cxh[r * 72 + c] = 0; cxl[r * 72 + c] = 0;
        }
    }
    float hp[4];
#pragma unroll
    for (int i = 0; i < 4; ++i)
        hp[i] = rowok ? enc_lds[(q * 4 + i) * 2048 + jw + ln] : 0.f;
    __syncthreads();

    for (int t = 0; t < 32; ++t) {
        // prefetch next step's x-gates: dec_in[t+1] = tgt[t]
        float xgn[3][4];
        {
            int tn = (t >= 31) ? 30 : t;
#pragma unroll
            for (int i = 0; i < 4; ++i) {
                int rowv = b0 + ((q * 4 + i) & 7);
                int id = tgt_ids[rowv * 32 + tn];
#pragma unroll
                for (int g = 0; g < 3; ++g) xgn[g][i] = xpvd[id * 192 + g * 64 + jw + ln];
            }
        }
        bf16x8 ah0 = load_afrag(&hqh[ln * 72 + q * 8]);
        bf16x8 ah1 = load_afrag(&hqh[ln * 72 + 32 + q * 8]);
        bf16x8 al0 = load_afrag(&hql[ln * 72 + q * 8]);
        bf16x8 al1 = load_afrag(&hql[ln * 72 + 32 + q * 8]);
        // edl = exp(2*(h@Wd + bd))
        {
            f32x4 a = {0.f, 0.f, 0.f, 0.f};
            a = mfma16(al0, wdh[0].v, a);
            a = mfma16(ah0, wdl[0].v, a);
            a = mfma16(ah0, wdh[0].v, a);
            a = mfma16(al1, wdh[1].v, a);
            a = mfma16(ah1, wdl[1].v, a);
            a = mfma16(ah1, wdh[1].v, a);
            if (rowok) {
#pragma unroll
                for (int i = 0; i < 4; ++i)
                    edl[(q * 4 + i) * 72 + jw + ln] = __expf((a[i] + bd_) * 2.0f);
            }
        }
        __syncthreads();
        // scores + softmax over S: E = E_d * E_e; tanh = 1 - 2/(E+1)
        {
            const int bb2 = tid >> 5, sidx = tid & 31;
            const float* dp = &edl[bb2 * 72];
            float av0 = 0.f, av1 = 0.f, av2 = 0.f, av3 = 0.f;
#pragma unroll
            for (int a4 = 0; a4 < 16; ++a4) {
                f32x4 dv = *(const f32x4*)(dp + a4 * 4);
                av0 += vl[a4 * 4 + 0] * rcp_(__builtin_fmaf(dv[0], Ee[a4 * 4 + 0], 1.0f));
                av1 += vl[a4 * 4 + 1] * rcp_(__builtin_fmaf(dv[1], Ee[a4 * 4 + 1], 1.0f));
                av2 += vl[a4 * 4 + 2] * rcp_(__builtin_fmaf(dv[2], Ee[a4 * 4 + 2], 1.0f));
                av3 += vl[a4 * 4 + 3] * rcp_(__builtin_fmaf(dv[3], Ee[a4 * 4 + 3], 1.0f));
            }
            float logit = SVB - 2.0f * ((av0 + av1) + (av2 + av3));
            float m = logit;
#pragma unroll
            for (int off = 16; off > 0; off >>= 1) m = fmaxf(m, __shfl_xor(m, off, 32));
            float e2 = __expf(logit - m);
            float ssum = e2;
#pragma unroll
            for (int off = 16; off > 0; off >>= 1) ssum += __shfl_xor(ssum, off, 32);
            wl[bb2 * 36 + sidx] = e2 * rcp_(ssum);
        }
        __syncthreads();
        // ctx = sum_s w[s] * encoded[b,s,:]  — LDS-only, wave-per-row sweep
#pragma unroll
        for (int rr2 = 0; rr2 < 2; ++rr2) {
            const int b = rr2 * 4 + w;
            float c0 = 0.f, c1 = 0.f, c2 = 0.f, c3 = 0.f;
#pragma unroll
            for (int s4 = 0; s4 < 8; ++s4) {
                const int s = s4 * 4 + q;
                const float ww = wl[b * 36 + s];
                f32x4 ev = *(const f32x4*)(&enc_lds[b * 2048 + s * 64 + ln * 4]);
                c0 += ww * ev[0]; c1 += ww * ev[1];
                c2 += ww * ev[2]; c3 += ww * ev[3];
            }
            c0 += __shfl_xor(c0, 16); c0 += __shfl_xor(c0, 32);
            c1 += __shfl_xor(c1, 16); c1 += __shfl_xor(c1, 32);
            c2 += __shfl_xor(c2, 16); c2 += __shfl_xor(c2, 32);
            c3 += __shfl_xor(c3, 16); c3 += __shfl_xor(c3, 32);
            if (q == 0) {
                u16x4 vh, vo;
                u16 th, tl2;
                split2(c0, th, tl2); vh[0] = th; vo[0] = tl2;
                split2(c1, th, tl2); vh[1] = th; vo[1] = tl2;
                split2(c2, th, tl2); vh[2] = th; vo[2] = tl2;
                split2(c3, th, tl2); vh[3] = th; vo[3] = tl2;
                *(u16x4*)(&cxh[b * 72 + ln * 4]) = vh;
                *(u16x4*)(&cxl[b * 72 + ln * 4]) = vo;
            }
        }
        __syncthreads();
        // GRU gates: ax[g] = ctx@Wc (input path), ahh[g] = h@U (recurrent)
        bf16x8 ac0 = load_afrag(&cxh[ln * 72 + q * 8]);
        bf16x8 ac1 = load_afrag(&cxh[ln * 72 + 32 + q * 8]);
        bf16x8 al2 = load_afrag(&cxl[ln * 72 + q * 8]);
        bf16x8 al3 = load_afrag(&cxl[ln * 72 + 32 + q * 8]);
        f32x4 ax[3], ahh[3];
#pragma unroll
        for (int g = 0; g < 3; ++g) {
            f32x4 a = {0.f, 0.f, 0.f, 0.f};
            a = mfma16(al2, wch[g][0].v, a);
            a = mfma16(ac0, wcl[g][0].v, a);
            a = mfma16(ac0, wch[g][0].v, a);
            a = mfma16(al3, wch[g][1].v, a);
            a = mfma16(ac1, wcl[g][1].v, a);
            a = mfma16(ac1, wch[g][1].v, a);
            ax[g] = a;
            f32x4 h = {0.f, 0.f, 0.f, 0.f};
            h = mfma16(al0, ufh[g][0].v, h);
            h = mfma16(ah0, ufl[g][0].v, h);
            h = mfma16(ah0, ufh[g][0].v, h);
            h = mfma16(al1, ufh[g][1].v, h);
            h = mfma16(ah1, ufl[g][1].v, h);
            h = mfma16(ah1, ufh[g][1].v, h);
            ahh[g] = h;
        }
        float nh[4];
#pragma unroll
        for (int i = 0; i < 4; ++i) {
            int rowg = b0 + q * 4 + i;
            float zz = sigm_(xg[0][i] + ax[0][i] + ahh[0][i] + b1[0]);
            float rr = sigm_(xg[1][i] + ax[1][i] + ahh[1][i] + b1[1]);
            float nn = tanh_(xg[2][i] + ax[2][i] + rr * (ahh[2][i] + b1[2]));
            nh[i] = zz * hp[i] + (1.0f - zz) * nn;  hp[i] = nh[i];
            if (rowok) {
                int gidx = (rowg * 32 + t) * 64 + jw + ln;
                u16 hi, lo; split2(nh[i], hi, lo);
                hid_hi[gidx] = hi; hid_lo[gidx] = lo;
                hqh[(q * 4 + i) * 72 + jw + ln] = hi;
                hql[(q * 4 + i) * 72 + jw + ln] = lo;
            }
        }
        // note: h-tile writes are safe here — all hq reads happened before
        // barrier 1 of this step; barrier below orders them for step t+1.
        __syncthreads();
#pragma unroll
        for (int g = 0; g < 3; ++g)
#pragma unroll
            for (int i = 0; i < 4; ++i) xg[g][i] = xgn[g][i];
    }
}

// ---------------------------------------------------------------------------
extern "C" void kernel_launch(void* const* d_in, const int* in_sizes, int n_in,
                              void* d_out, int out_size, void* d_ws, size_t ws_size,
                              hipStream_t stream) {
    const int*   src_ids = (const int*)d_in[0];
    const int*   tgt_ids = (const int*)d_in[1];
    const float* src_emb = (const float*)d_in[2];
    const float* enc_Wf  = (const float*)d_in[3];
    const float* enc_Uf  = (const float*)d_in[4];
    const float* enc_bf  = (const float*)d_in[5];
    const float* enc_Wb  = (const float*)d_in[6];
    const float* enc_Ub  = (const float*)d_in[7];
    const float* enc_bb  = (const float*)d_in[8];
    const float* attn_We = (const float*)d_in[9];
    const float* attn_be = (const float*)d_in[10];
    const float* attn_Wd = (const float*)d_in[11];
    const float* attn_bd = (const float*)d_in[12];
    const float* attn_v  = (const float*)d_in[13];
    const float* attn_bv = (const float*)d_in[14];
    const float* dec_W   = (const float*)d_in[15];
    const float* dec_U   = (const float*)d_in[16];
    const float* dec_b   = (const float*)d_in[17];
    const float* out_W   = (const float*)d_in[18];
    const float* out_b   = (const float*)d_in[19];

    // ws layout (u16 units). fwd [0,16)/[16,32) MiB, bwd [32,48)/[48,64),
    // encpT [64,80), xpv_f/xpv_b/xpvd after 80 MiB. hid reuses fwd planes
    // (dec reads its own rows before overwriting them).
    u16* ws = (u16*)d_ws;
    u16* fwd_hi = ws;
    u16* fwd_lo = ws +  8388608;
    u16* bwd_hi = ws + 16777216;
    u16* bwd_lo = ws + 25165824;
    u16* encpT  = ws + 33554432;
    float* xpv_f = (float*)(ws + 41943040);
    float* xpv_b = (float*)(ws + 42041344);
    float* xpvd  = (float*)(ws + 42139648);
    u16* hid_hi = fwd_hi;
    u16* hid_lo = fwd_lo;

    dim3 blk(256);
    gemm_hl<0, 128, 192><<<4, blk, 0, stream>>>(
        src_emb, nullptr, nullptr, nullptr, nullptr, enc_Wf, enc_bf, xpv_f, nullptr);
    gemm_hl<0, 128, 192><<<4, blk, 0, stream>>>(
        src_emb, nullptr, nullptr, nullptr, nullptr, enc_Wb, enc_bb, xpv_b, nullptr);
    gemm_hl<1, 64, 192><<<4, blk, 0, stream>>>(
        out_W, nullptr, nullptr, nullptr, nullptr, dec_W, dec_b, xpvd, nullptr);
    enc8<<<1024, blk, 0, stream>>>(src_ids, xpv_f, xpv_b, enc_Uf, enc_bf,
                                   enc_Ub, enc_bb, fwd_hi, fwd_lo, bwd_hi, bwd_lo);
    gemm_hl<2, 64, 64><<<2048, blk, 0, stream>>>(
        nullptr, fwd_hi, fwd_lo, bwd_hi, bwd_lo, attn_We, attn_be, nullptr, encpT);
    dec_kernel<<<512, blk, 0, stream>>>(tgt_ids, xpvd, fwd_hi, fwd_lo, bwd_hi,
                                        bwd_lo, encpT, dec_U, dec_W, dec_b,
                                        attn_Wd, attn_bd, attn_v, attn_bv,
                                        hid_hi, hid_lo);
    gemm_hl<3, 64, 256><<<2048, blk, 0, stream>>>(
        nullptr, hid_hi, hid_lo, nullptr, nullptr, out_W, out_b, (float*)d_out, nullptr);
}